// Round 8
// baseline (2228.086 us; speedup 1.0000x reference)
//
#include <hip/hip_runtime.h>

typedef _Float16 f16;
typedef _Float16 f16x8 __attribute__((ext_vector_type(8)));
typedef float f32x4 __attribute__((ext_vector_type(4)));

__device__ __forceinline__ f32x4 mfma16(f16x8 a, f16x8 b, f32x4 c) {
    return __builtin_amdgcn_mfma_f32_16x16x32_f16(a, b, c, 0, 0, 0);
}

// ---------------- main implicit-GEMM 3x3 conv, f16 MFMA ----------------
// in : [H+2][W+2][IC] padded NHWC f16 (zero halo), per-item stride inStride
// wt : [9][OC][IC] f16 (t = ky*3+kx)
// Wave tile: MT m-tiles (MT*16 pos) x NT n-tiles (NT*16 oc). Block: WY x WO waves.
// acc = MT*NT*4 VGPRs; launch_bounds(256,4) targets <=128 VGPR -> 4 waves/SIMD.
template<int IC, int OC, int BX, int WY, int WO, int MT, int NT, bool POOL>
__global__ __launch_bounds__(256, 4) void convmf_k(
    const f16* __restrict__ in, const f16* __restrict__ wt,
    const float* __restrict__ bias, f16* __restrict__ out,
    int H, int W, int ocBlocks, long inStride, long outStride)
{
    constexpr int WROWS = MT * 16 / BX;
    constexpr int BROWS = WROWS * WY;
    constexpr int SR = BROWS + 2;
    constexpr int SC = BX + 2;
    constexpr int LOG = (BX == 64) ? 6 : 5;
    static_assert(!POOL || (BX == 64 && MT == 8), "pool path assumes BX==64, MT==8");
    __shared__ f16 lds[SR * SC * 40];

    const int tid  = threadIdx.x;
    const int lane = tid & 63;
    const int wv   = tid >> 6;
    const int wy   = wv / WO;
    const int wo   = wv % WO;
    const int lm   = lane & 15;
    const int lk   = lane >> 4;
    const int x0   = blockIdx.x * BX;
    const int y0   = blockIdx.y * BROWS;
    const int zb   = blockIdx.z;
    const int n    = zb / ocBlocks;
    const int oc0  = (zb - n * ocBlocks) * (16 * NT * WO) + wo * (16 * NT);
    in  += (long)n * inStride;
    out += (long)n * outStride;

    f32x4 acc[MT][NT];
#pragma unroll
    for (int mt = 0; mt < MT; ++mt)
#pragma unroll
        for (int nt = 0; nt < NT; ++nt)
            acc[mt][nt] = (f32x4){0.f, 0.f, 0.f, 0.f};

    const int Wp = W + 2;
    for (int ic0 = 0; ic0 < IC; ic0 += 32) {
        if (ic0) __syncthreads();
        const f16* ip = in + ((long)y0 * Wp + x0) * IC + ic0;
        constexpr int TASKS = SR * SC * 4;
        for (int s = tid; s < TASKS; s += 256) {
            int r    = s / (SC * 4);
            int rem  = s - r * (SC * 4);
            int xcol = rem >> 2;
            int g    = rem & 3;
            f16x8 v = *(const f16x8*)(ip + ((long)r * Wp + xcol) * IC + g * 8);
            *(f16x8*)&lds[(r * SC + xcol) * 40 + g * 8] = v;
        }
        __syncthreads();

        for (int t = 0; t < 9; ++t) {
            int dy = t / 3, dx = t - dy * 3;
            const f16* wp = wt + ((long)t * OC + oc0) * IC + ic0 + lk * 8;
            f16x8 bfr[NT];
#pragma unroll
            for (int nt = 0; nt < NT; ++nt)
                bfr[nt] = *(const f16x8*)(wp + (nt * 16 + lm) * IC);
#pragma unroll
            for (int mt = 0; mt < MT; ++mt) {
                int pos = mt * 16 + lm;
                int xx = pos & (BX - 1);
                int yy = wy * WROWS + (pos >> LOG);
                f16x8 a = *(const f16x8*)&lds[((yy + dy) * SC + xx + dx) * 40 + lk * 8];
#pragma unroll
                for (int nt = 0; nt < NT; ++nt)
                    acc[mt][nt] = mfma16(a, bfr[nt], acc[mt][nt]);
            }
        }
    }

    if constexpr (!POOL) {
#pragma unroll
        for (int nt = 0; nt < NT; ++nt) {
            int oc = oc0 + nt * 16 + lm;
            float bs = bias[oc];
#pragma unroll
            for (int mt = 0; mt < MT; ++mt) {
#pragma unroll
                for (int r = 0; r < 4; ++r) {
                    int pos = mt * 16 + lk * 4 + r;
                    int xx = pos & (BX - 1);
                    int yy = wy * WROWS + (pos >> LOG);
                    float v = fmaxf(acc[mt][nt][r] + bs, 0.f);
                    out[((long)(y0 + yy + 1) * (W + 2) + (x0 + xx + 1)) * OC + oc] = (f16)v;
                }
            }
        }
    } else {
        const int Wo = W >> 1;
#pragma unroll
        for (int nt = 0; nt < NT; ++nt) {
            int oc = oc0 + nt * 16 + lm;
            float bs = bias[oc];
#pragma unroll
            for (int mt = 0; mt < 4; ++mt) {
#pragma unroll
                for (int r = 0; r < 4; r += 2) {
                    float v = fmaxf(fmaxf(acc[mt][nt][r], acc[mt][nt][r + 1]),
                                    fmaxf(acc[mt + 4][nt][r], acc[mt + 4][nt][r + 1]));
                    v = fmaxf(v + bs, 0.f);
                    int pos = mt * 16 + lk * 4 + r;
                    int xo = pos >> 1;
                    out[((long)((y0 >> 1) + wy + 1) * (Wo + 2) + ((x0 >> 1) + xo + 1)) * OC + oc] = (f16)v;
                }
            }
        }
    }
}

// ---------------- fused conv1(IC=2)+conv2(64->64)+pool, occupancy retune ----------------
// Block: 64 cols x 4 conv2-rows. Waves: wy=wv>>1 (row-slice), wo=wv&1 (oc half).
// conv1 tile: 6x66 pixels x 32 ic (per cc chunk) in LDS; conv2 MT=8,NT=2.
__global__ __launch_bounds__(256, 4) void conv12_k(
    const float* __restrict__ x,   // [8][2][512][512] fp32
    const f16* __restrict__ wt1,   // [64][32], k = 2t+ic, zero-padded
    const float* __restrict__ b1,
    const f16* __restrict__ wt2,   // [9][64][64]
    const float* __restrict__ b2,
    f16* __restrict__ p1, int itemBase, long outStride)
{
    __shared__ f16 ldsx[8 * 68 * 2];     // x tile [r][c][ch]
    __shared__ f16 a1t[6 * 66 * 40];     // conv1 out tile [pix][40] (32 ic + pad)
    const int tid = threadIdx.x;
    const int lane = tid & 63;
    const int wv = tid >> 6;
    const int wy = wv >> 1;
    const int wo = wv & 1;
    const int lm = lane & 15;
    const int lk = lane >> 4;
    const int x0 = blockIdx.x * 64;
    const int y0 = blockIdx.y * 4;
    const float* xb = x + (long)(itemBase + blockIdx.z) * 2 * 512 * 512;
    f16* out = p1 + (long)blockIdx.z * outStride;

    // stage x tile (8 rows x 68 cols x 2 ch), bounds -> 0, cvt f16
    for (int s = tid; s < 8 * 68 * 2; s += 256) {
        int ch = s & 1;
        int v = s >> 1;
        int r = v / 68, c = v - r * 68;
        int gy = y0 + r - 2, gx = x0 + c - 2;
        f16 val = (f16)0.f;
        if ((unsigned)gy < 512u && (unsigned)gx < 512u)
            val = (f16)xb[((long)ch * 512 + gy) * 512 + gx];
        ldsx[s] = val;
    }
    __syncthreads();

    f32x4 acc[8][2];
#pragma unroll
    for (int mt = 0; mt < 8; ++mt)
#pragma unroll
        for (int nt = 0; nt < 2; ++nt)
            acc[mt][nt] = (f32x4){0.f, 0.f, 0.f, 0.f};

    for (int cc = 0; cc < 2; ++cc) {
        if (cc) __syncthreads();   // conv2 chunk-0 reads done before overwrite

        // ---- conv1 -> a1t (ocs cc*32..cc*32+31), 25 tiles strided over 4 waves ----
        {
            float bs0 = b1[cc * 32 + lm];
            float bs1 = b1[cc * 32 + 16 + lm];
            f16x8 bf0 = *(const f16x8*)(wt1 + (cc * 32 + lm) * 32 + lk * 8);
            f16x8 bf1 = *(const f16x8*)(wt1 + (cc * 32 + 16 + lm) * 32 + lk * 8);
            for (int tile = wv; tile < 25; tile += 4) {
                const int pixA = tile * 16 + lm;
                const int pixg = (pixA < 396) ? pixA : 0;
                int rA = (pixg * 993) >> 16;   // /66, valid pix<672
                int cA = pixg - rA * 66;
                f16x8 af;
#pragma unroll
                for (int j = 0; j < 8; ++j) {
                    int k = lk * 8 + j;
                    f16 v = (f16)0.f;
                    if (k < 18) {
                        int t = k >> 1, ic = k & 1;
                        int dy = (t * 22) >> 6;  // /3 for t<9
                        int dx = t - 3 * dy;
                        v = ldsx[((rA + dy) * 68 + (cA + dx)) * 2 + ic];
                    }
                    af[j] = v;
                }
                f32x4 c0 = (f32x4){0.f, 0.f, 0.f, 0.f};
                f32x4 c1 = (f32x4){0.f, 0.f, 0.f, 0.f};
                c0 = mfma16(af, bf0, c0);
                c1 = mfma16(af, bf1, c1);
#pragma unroll
                for (int rr = 0; rr < 4; ++rr) {
                    int pix = tile * 16 + lk * 4 + rr;
                    if (pix < 396) {
                        int rP = (pix * 993) >> 16;
                        int cP = pix - rP * 66;
                        bool valid = ((unsigned)(y0 + rP - 1) < 512u) &&
                                     ((unsigned)(x0 + cP - 1) < 512u);
                        float v0 = valid ? fmaxf(c0[rr] + bs0, 0.f) : 0.f;
                        float v1 = valid ? fmaxf(c1[rr] + bs1, 0.f) : 0.f;
                        a1t[pix * 40 + lm] = (f16)v0;
                        a1t[pix * 40 + 16 + lm] = (f16)v1;
                    }
                }
            }
        }
        __syncthreads();

        // ---- conv2 chunk cc (t-loop from a1t), MT=8 x NT=2 ----
        const int ic0 = cc * 32;
        for (int t = 0; t < 9; ++t) {
            int dy = t / 3, dx = t - dy * 3;
            const f16* wp = wt2 + ((long)t * 64 + wo * 32) * 64 + ic0 + lk * 8;
            f16x8 bb0 = *(const f16x8*)(wp + (0 * 16 + lm) * 64);
            f16x8 bb1 = *(const f16x8*)(wp + (1 * 16 + lm) * 64);
#pragma unroll
            for (int mt = 0; mt < 8; ++mt) {
                int pos = mt * 16 + lm;
                int xx = pos & 63;
                int yy = wy * 2 + (pos >> 6);
                f16x8 a = *(const f16x8*)&a1t[((yy + dy) * 66 + xx + dx) * 40 + lk * 8];
                acc[mt][0] = mfma16(a, bb0, acc[mt][0]);
                acc[mt][1] = mfma16(a, bb1, acc[mt][1]);
            }
        }
    }

    // pooled epilogue -> p1 [258][258][64]
#pragma unroll
    for (int nt = 0; nt < 2; ++nt) {
        int oc = wo * 32 + nt * 16 + lm;
        float bs = b2[oc];
#pragma unroll
        for (int mt = 0; mt < 4; ++mt) {
#pragma unroll
            for (int r = 0; r < 4; r += 2) {
                float v = fmaxf(fmaxf(acc[mt][nt][r], acc[mt][nt][r + 1]),
                                fmaxf(acc[mt + 4][nt][r], acc[mt + 4][nt][r + 1]));
                v = fmaxf(v + bs, 0.f);
                int pos = mt * 16 + lk * 4 + r;
                int xo = pos >> 1;
                out[((long)((y0 >> 1) + wy + 1) * 258 + ((x0 >> 1) + xo + 1)) * 64 + oc] = (f16)v;
            }
        }
    }
}

// ---------------- fused heads (loc+conf+regr) as one 16-oc MFMA conv ----------------
template<int BX>
__global__ __launch_bounds__(256) void headconv_k(
    const f16* __restrict__ s, long sStride, const f16* __restrict__ wth,
    const float* __restrict__ lb, const float* __restrict__ cb, const float* __restrict__ rb,
    float* __restrict__ loc, float* __restrict__ conf, float* __restrict__ regr,
    int W, int posoff)
{
    constexpr int BY = (BX == 64) ? 1 : 2;
    constexpr int SR = BY + 2, SC = BX + 2;
    constexpr int LOG = (BX == 64) ? 6 : 5;
    __shared__ f16 lds[SR * SC * 40];
    const int tid = threadIdx.x;
    const int lane = tid & 63;
    const int wv = tid >> 6;
    const int lm = lane & 15;
    const int lk = lane >> 4;
    const int y0 = blockIdx.y * BY;
    const int b = blockIdx.z;
    s += (long)b * sStride;

    f32x4 acc = (f32x4){0.f, 0.f, 0.f, 0.f};
    const int Wp = W + 2;
    for (int ic0 = 0; ic0 < 256; ic0 += 32) {
        if (ic0) __syncthreads();
        const f16* ip = s + (long)y0 * Wp * 256 + ic0;
        constexpr int TASKS = SR * SC * 4;
        for (int t = tid; t < TASKS; t += 256) {
            int r = t / (SC * 4);
            int rem = t - r * (SC * 4);
            int xcol = rem >> 2, g = rem & 3;
            f16x8 v = *(const f16x8*)(ip + ((long)r * Wp + xcol) * 256 + g * 8);
            *(f16x8*)&lds[(r * SC + xcol) * 40 + g * 8] = v;
        }
        __syncthreads();
        for (int t = 0; t < 9; ++t) {
            int dy = t / 3, dx = t - dy * 3;
            f16x8 bf = *(const f16x8*)(wth + ((long)t * 16 + lm) * 256 + ic0 + lk * 8);
            int pos = wv * 16 + lm;
            int xx = pos & (BX - 1), yy = pos >> LOG;
            f16x8 a = *(const f16x8*)&lds[((yy + dy) * SC + xx + dx) * 40 + lk * 8];
            acc = mfma16(a, bf, acc);
        }
    }
#pragma unroll
    for (int r = 0; r < 4; ++r) {
        int pos = wv * 16 + lk * 4 + r;
        int xx = pos & (BX - 1), yy = pos >> LOG;
        int P = posoff + (y0 + yy) * W + xx;
        float v = acc[r];
        if (lm < 2)       loc[((long)b * 5120 + P) * 2 + lm]       = v + lb[lm];
        else if (lm < 5)  conf[((long)b * 5120 + P) * 3 + (lm - 2)] = v + cb[lm - 2];
        else if (lm == 5) regr[(long)b * 5120 + P]                  = v + rb[0];
    }
}

// ---------------- small utility kernels ----------------
__global__ __launch_bounds__(256) void cvt_wt_k(const float* __restrict__ w, f16* __restrict__ wt,
                                                int OC, int IC)
{
    int idx = blockIdx.x * 256 + threadIdx.x;
    if (idx >= OC * IC) return;
    int oc = idx / IC, ic = idx - oc * IC;
#pragma unroll
    for (int t = 0; t < 9; ++t)
        wt[((long)t * OC + oc) * IC + ic] = (f16)w[(long)idx * 9 + t];
}

__global__ __launch_bounds__(64) void cvt_wt1_k(const float* __restrict__ w, f16* __restrict__ wt1)
{
    int oc = threadIdx.x;
#pragma unroll
    for (int k = 0; k < 32; ++k) {
        f16 v = (f16)0.f;
        if (k < 18) {
            int t = k >> 1, ic = k & 1;
            v = (f16)w[((long)oc * 2 + ic) * 9 + t];
        }
        wt1[oc * 32 + k] = v;
    }
}

__global__ __launch_bounds__(256) void cvt_wth_k(const float* __restrict__ lw, const float* __restrict__ cw,
                                                 const float* __restrict__ rw, f16* __restrict__ wth)
{
    int idx = blockIdx.x * 256 + threadIdx.x;
    if (idx >= 9 * 16 * 256) return;
    int t = idx / (16 * 256);
    int r = (idx / 256) & 15;
    int ic = idx & 255;
    float v = 0.f;
    if (r < 2)      v = lw[((long)r * 256 + ic) * 9 + t];
    else if (r < 5) v = cw[((long)(r - 2) * 256 + ic) * 9 + t];
    else if (r == 5) v = rw[(long)ic * 9 + t];
    wth[((long)t * 16 + r) * 256 + ic] = (f16)v;
}

__global__ __launch_bounds__(256) void halo_k(f16* __restrict__ buf, int W, int H, int C,
                                              long stride, int items)
{
    int per = (2 * (W + 2) + 2 * H) * C;
    long total = (long)per * items;
    long idx = (long)blockIdx.x * 256 + threadIdx.x;
    if (idx >= total) return;
    int n = idx / per;
    int j = idx - (long)n * per;
    int c = j % C, p = j / C;
    int row, col;
    if (p < W + 2) { row = 0; col = p; }
    else if (p < 2 * (W + 2)) { row = H + 1; col = p - (W + 2); }
    else { int q = p - 2 * (W + 2); row = 1 + (q >> 1); col = (q & 1) ? (W + 1) : 0; }
    buf[(long)n * stride + ((long)row * (W + 2) + col) * C + c] = (f16)0.f;
}

__global__ __launch_bounds__(256) void l2n_k(const f16* __restrict__ in, const float* __restrict__ g,
                                             f16* __restrict__ out, int W, long stride, int total)
{
    int i = blockIdx.x * 256 + threadIdx.x;
    if (i >= total) return;
    int b = i / (W * W);
    int rem = i - b * W * W;
    int y = rem / W, x = rem - y * W;
    long off = (long)b * stride + ((long)(y + 1) * (W + 2) + x + 1) * 256;
    const f16* p = in + off;
    f16* q = out + off;
    float s = 0.f;
    for (int gg = 0; gg < 32; ++gg) {
        f16x8 v = *(const f16x8*)(p + gg * 8);
#pragma unroll
        for (int j = 0; j < 8; ++j) { float f = (float)v[j]; s = fmaf(f, f, s); }
    }
    float inv = 1.f / (sqrtf(s) + 1e-10f);
    for (int gg = 0; gg < 32; ++gg) {
        f16x8 v = *(const f16x8*)(p + gg * 8);
        f16x8 o;
#pragma unroll
        for (int j = 0; j < 8; ++j) o[j] = (f16)(g[gg * 8 + j] * ((float)v[j] * inv));
        *(f16x8*)(q + gg * 8) = o;
    }
}

__global__ __launch_bounds__(256) void mp_k(const f16* __restrict__ in, f16* __restrict__ out)
{
    int idx = blockIdx.x * 256 + threadIdx.x;
    if (idx >= 8 * 32 * 32 * 32) return;
    int gg = idx & 31;
    int xo = (idx >> 5) & 31;
    int yo = (idx >> 10) & 31;
    int b = idx >> 15;
    const f16* p = in + (long)b * 1115136 + ((long)(2 * yo + 1) * 66 + 2 * xo + 1) * 256 + gg * 8;
    f16x8 a0 = *(const f16x8*)p;
    f16x8 a1 = *(const f16x8*)(p + 256);
    f16x8 a2 = *(const f16x8*)(p + 66 * 256);
    f16x8 a3 = *(const f16x8*)(p + 66 * 256 + 256);
    f16x8 o;
#pragma unroll
    for (int j = 0; j < 8; ++j)
        o[j] = (f16)fmaxf(fmaxf((float)a0[j], (float)a1[j]), fmaxf((float)a2[j], (float)a3[j]));
    *(f16x8*)(out + (long)b * 295936 + ((long)(yo + 1) * 34 + xo + 1) * 256 + gg * 8) = o;
}

__global__ __launch_bounds__(256) void priors_k(float* __restrict__ out)
{
    int r = blockIdx.x * 256 + threadIdx.x;
    if (r >= 5120) return;
    float cx, cy;
    if (r < 4096) {
        int i = r >> 6, j = r & 63;
        cx = (j + 0.5f) / 64.0f; cy = (i + 0.5f) / 64.0f;
    } else {
        int rr = r - 4096;
        int i = rr >> 5, j = rr & 31;
        cx = (j + 0.5f) / 32.0f; cy = (i + 0.5f) / 32.0f;
    }
    out[2 * r] = cx;
    out[2 * r + 1] = cy;
}

// ---------------- launch ----------------
extern "C" void kernel_launch(void* const* d_in, const int* in_sizes, int n_in,
                              void* d_out, int out_size, void* d_ws, size_t ws_size,
                              hipStream_t stream)
{
    const float* x  = (const float*)d_in[0];
    const float* w1 = (const float*)d_in[1];  const float* b1 = (const float*)d_in[2];
    const float* w2 = (const float*)d_in[3];  const float* b2 = (const float*)d_in[4];
    const float* w3 = (const float*)d_in[5];  const float* b3 = (const float*)d_in[6];
    const float* w4 = (const float*)d_in[7];  const float* b4 = (const float*)d_in[8];
    const float* w5 = (const float*)d_in[9];  const float* b5 = (const float*)d_in[10];
    const float* w6 = (const float*)d_in[11]; const float* b6 = (const float*)d_in[12];
    const float* w7 = (const float*)d_in[13]; const float* b7 = (const float*)d_in[14];
    const float* w8 = (const float*)d_in[15]; const float* b8 = (const float*)d_in[16];
    const float* g1 = (const float*)d_in[17]; const float* g2 = (const float*)d_in[18];
    const float* lw1 = (const float*)d_in[19]; const float* lb1 = (const float*)d_in[20];
    const float* lw2 = (const float*)d_in[21]; const float* lb2 = (const float*)d_in[22];
    const float* cw1 = (const float*)d_in[23]; const float* cb1 = (const float*)d_in[24];
    const float* cw2 = (const float*)d_in[25]; const float* cb2 = (const float*)d_in[26];
    const float* rw1 = (const float*)d_in[27]; const float* rb1 = (const float*)d_in[28];
    const float* rw2 = (const float*)d_in[29]; const float* rb2 = (const float*)d_in[30];

    f16* wsh = (f16*)d_ws;
    // fixed region (f16 units)
    f16* wt2  = wsh + 0;         // 36864
    f16* wt3  = wsh + 36864;     // 73728
    f16* wt4  = wsh + 110592;    // 147456
    f16* wt5  = wsh + 258048;    // 294912
    f16* wt6  = wsh + 552960;    // 589824
    f16* wt7  = wsh + 1142784;   // 589824
    f16* wt8  = wsh + 1732608;   // 589824
    f16* wt1  = wsh + 2322432;   // 2048
    f16* wth1 = wsh + 2324480;   // 36864
    f16* wth2 = wsh + 2361344;   // 36864
    f16* x6p  = wsh + 2398208;   // 8*66*66*256 = 8921088
    const long PI = 11319296;    // group region base

    // per-item slot: R1 (p1 258x258x64 | p2 130x130x128) + R2 (a3 258x258x128 | a5 130x130x256)
    const long R1S = 4260096;
    const long PS  = 12780288;   // R1S + 8520192
    const long PH2 = 18391040;   // phase-2 footprint (s1..s2)

    int G = 1;
    for (int g = 8; g >= 1; g >>= 1) {
        long ext = (long)g * PS; if (ext < PH2) ext = PH2;
        if (2.0 * (double)(PI + ext) <= (double)ws_size) { G = g; break; }
    }
    const int NGRP = 8 / G;

    f16* p1 = wsh + PI;          // slot stride PS (aliased: p2)
    f16* a3 = wsh + PI + R1S;    // slot stride PS (aliased: a5)
    f16* p2 = p1;
    f16* a5 = a3;
    // phase-2 (after group loop, group region dead)
    f16* s1 = wsh + PI;
    f16* p4 = wsh + PI + 8921088;
    f16* a7 = wsh + PI + 11288576;
    f16* a8 = wsh + PI + 13656064;
    f16* s2 = wsh + PI + 16023552;

    float* loc  = (float*)d_out;
    float* conf = loc + 81920;
    float* regr = loc + 204800;
    float* pri  = loc + 245760;

    // weight conversions
    cvt_wt_k<<<dim3((64 * 64 + 255) / 256), 256, 0, stream>>>(w2, wt2, 64, 64);
    cvt_wt_k<<<dim3((128 * 64 + 255) / 256), 256, 0, stream>>>(w3, wt3, 128, 64);
    cvt_wt_k<<<dim3((128 * 128 + 255) / 256), 256, 0, stream>>>(w4, wt4, 128, 128);
    cvt_wt_k<<<dim3((256 * 128 + 255) / 256), 256, 0, stream>>>(w5, wt5, 256, 128);
    cvt_wt_k<<<dim3((256 * 256 + 255) / 256), 256, 0, stream>>>(w6, wt6, 256, 256);
    cvt_wt_k<<<dim3((256 * 256 + 255) / 256), 256, 0, stream>>>(w7, wt7, 256, 256);
    cvt_wt_k<<<dim3((256 * 256 + 255) / 256), 256, 0, stream>>>(w8, wt8, 256, 256);
    cvt_wt1_k<<<dim3(1), 64, 0, stream>>>(w1, wt1);
    cvt_wth_k<<<dim3(144), 256, 0, stream>>>(lw1, cw1, rw1, wth1);
    cvt_wth_k<<<dim3(144), 256, 0, stream>>>(lw2, cw2, rw2, wth2);

    // conv12..conv6, G items per dispatch; aliased halos re-zeroed in order
    for (int grp = 0; grp < NGRP; ++grp) {
        f16* x6g = x6p + (long)grp * G * 1115136;
        halo_k<<<dim3((G * (2 * 258 + 2 * 256) * 64 + 255) / 256), 256, 0, stream>>>(p1, 256, 256, 64, PS, G);
        halo_k<<<dim3((G * (2 * 258 + 2 * 256) * 128 + 255) / 256), 256, 0, stream>>>(a3, 256, 256, 128, PS, G);
        conv12_k<<<dim3(8, 128, G), 256, 0, stream>>>(x, wt1, b1, wt2, b2, p1, grp * G, PS);
        convmf_k<64, 128, 64, 2, 2, 8, 2, false><<<dim3(4, 64, 2 * G), 256, 0, stream>>>(
            p1, wt3, b3, a3, 256, 256, 2, PS, PS);
        halo_k<<<dim3((G * (2 * 130 + 2 * 128) * 128 + 255) / 256), 256, 0, stream>>>(p2, 128, 128, 128, PS, G);
        convmf_k<128, 128, 64, 2, 2, 8, 2, true><<<dim3(4, 64, 2 * G), 256, 0, stream>>>(
            a3, wt4, b4, p2, 256, 256, 2, PS, PS);
        halo_k<<<dim3((G * (2 * 130 + 2 * 128) * 256 + 255) / 256), 256, 0, stream>>>(a5, 128, 128, 256, PS, G);
        convmf_k<128, 256, 64, 2, 2, 8, 2, false><<<dim3(2, 32, 4 * G), 256, 0, stream>>>(
            p2, wt5, b5, a5, 128, 128, 4, PS, PS);
        convmf_k<256, 256, 64, 2, 2, 8, 2, true><<<dim3(2, 32, 4 * G), 256, 0, stream>>>(
            a5, wt6, b6, x6g, 128, 128, 4, PS, 1115136);
    }

    // phase-2 halos (group region now dead)
    halo_k<<<dim3((8 * (2 * 66 + 2 * 64) * 256 + 255) / 256), 256, 0, stream>>>(s1, 64, 64, 256, 1115136, 8);
    halo_k<<<dim3((8 * (2 * 34 + 2 * 32) * 256 + 255) / 256), 256, 0, stream>>>(p4, 32, 32, 256, 295936, 8);
    halo_k<<<dim3((8 * (2 * 34 + 2 * 32) * 256 + 255) / 256), 256, 0, stream>>>(a7, 32, 32, 256, 295936, 8);
    halo_k<<<dim3((8 * (2 * 34 + 2 * 32) * 256 + 255) / 256), 256, 0, stream>>>(s2, 32, 32, 256, 295936, 8);

    l2n_k<<<dim3((32768 + 255) / 256), 256, 0, stream>>>(x6p, g1, s1, 64, 1115136, 32768);
    mp_k<<<dim3((262144 + 255) / 256), 256, 0, stream>>>(x6p, p4);
    convmf_k<256, 256, 32, 2, 2, 4, 4, false><<<dim3(1, 8, 16), 256, 0, stream>>>(
        p4, wt7, b7, a7, 32, 32, 2, 295936, 295936);
    convmf_k<256, 256, 32, 2, 2, 4, 4, false><<<dim3(1, 8, 16), 256, 0, stream>>>(
        a7, wt8, b8, a8, 32, 32, 2, 295936, 295936);
    l2n_k<<<dim3((8192 + 255) / 256), 256, 0, stream>>>(a8, g2, s2, 32, 295936, 8192);

    headconv_k<64><<<dim3(1, 64, 8), 256, 0, stream>>>(
        s1, 1115136, wth1, lb1, cb1, rb1, loc, conf, regr, 64, 0);
    headconv_k<32><<<dim3(1, 16, 8), 256, 0, stream>>>(
        s2, 295936, wth2, lb2, cb2, rb2, loc, conf, regr, 32, 4096);
    priors_k<<<dim3(20), 256, 0, stream>>>(pri);

    (void)in_sizes; (void)n_in; (void)out_size; (void)ws_size;
}

// Round 9
// 1419.359 us; speedup vs baseline: 1.5698x; 1.5698x over previous
//
#include <hip/hip_runtime.h>

typedef _Float16 f16;
typedef _Float16 f16x8 __attribute__((ext_vector_type(8)));
typedef float f32x4 __attribute__((ext_vector_type(4)));

__device__ __forceinline__ f32x4 mfma16(f16x8 a, f16x8 b, f32x4 c) {
    return __builtin_amdgcn_mfma_f32_16x16x32_f16(a, b, c, 0, 0, 0);
}

// ---------------- main implicit-GEMM 3x3 conv, f16 MFMA (round-7 proven, untouched) ----------------
template<int IC, int OC, int BX, int WY, int WO, int MT, bool POOL>
__global__ __launch_bounds__(256) void convmf_k(
    const f16* __restrict__ in, const f16* __restrict__ wt,
    const float* __restrict__ bias, f16* __restrict__ out,
    int H, int W, int ocBlocks, long inStride, long outStride)
{
    constexpr int WROWS = MT * 16 / BX;
    constexpr int BROWS = WROWS * WY;
    constexpr int SR = BROWS + 2;
    constexpr int SC = BX + 2;
    constexpr int LOG = (BX == 64) ? 6 : 5;
    static_assert(!POOL || (BX == 64 && MT == 8), "pool path assumes BX==64, MT==8");
    __shared__ f16 lds[SR * SC * 40];

    const int tid  = threadIdx.x;
    const int lane = tid & 63;
    const int wv   = tid >> 6;
    const int wy   = wv / WO;
    const int wo   = wv % WO;
    const int lm   = lane & 15;
    const int lk   = lane >> 4;
    const int x0   = blockIdx.x * BX;
    const int y0   = blockIdx.y * BROWS;
    const int zb   = blockIdx.z;
    const int n    = zb / ocBlocks;
    const int oc0  = (zb - n * ocBlocks) * (64 * WO) + wo * 64;
    in  += (long)n * inStride;
    out += (long)n * outStride;

    f32x4 acc[MT][4];
#pragma unroll
    for (int mt = 0; mt < MT; ++mt)
#pragma unroll
        for (int nt = 0; nt < 4; ++nt)
            acc[mt][nt] = (f32x4){0.f, 0.f, 0.f, 0.f};

    const int Wp = W + 2;
    for (int ic0 = 0; ic0 < IC; ic0 += 32) {
        if (ic0) __syncthreads();
        const f16* ip = in + ((long)y0 * Wp + x0) * IC + ic0;
        constexpr int TASKS = SR * SC * 4;
        for (int s = tid; s < TASKS; s += 256) {
            int r    = s / (SC * 4);
            int rem  = s - r * (SC * 4);
            int xcol = rem >> 2;
            int g    = rem & 3;
            f16x8 v = *(const f16x8*)(ip + ((long)r * Wp + xcol) * IC + g * 8);
            *(f16x8*)&lds[(r * SC + xcol) * 40 + g * 8] = v;
        }
        __syncthreads();

        for (int t = 0; t < 9; ++t) {
            int dy = t / 3, dx = t - dy * 3;
            const f16* wp = wt + ((long)t * OC + oc0) * IC + ic0 + lk * 8;
            f16x8 b0 = *(const f16x8*)(wp + (0 * 16 + lm) * IC);
            f16x8 b1 = *(const f16x8*)(wp + (1 * 16 + lm) * IC);
            f16x8 b2 = *(const f16x8*)(wp + (2 * 16 + lm) * IC);
            f16x8 b3 = *(const f16x8*)(wp + (3 * 16 + lm) * IC);
#pragma unroll
            for (int mt = 0; mt < MT; ++mt) {
                int pos = mt * 16 + lm;
                int xx = pos & (BX - 1);
                int yy = wy * WROWS + (pos >> LOG);
                f16x8 a = *(const f16x8*)&lds[((yy + dy) * SC + xx + dx) * 40 + lk * 8];
                acc[mt][0] = mfma16(a, b0, acc[mt][0]);
                acc[mt][1] = mfma16(a, b1, acc[mt][1]);
                acc[mt][2] = mfma16(a, b2, acc[mt][2]);
                acc[mt][3] = mfma16(a, b3, acc[mt][3]);
            }
        }
    }

    if constexpr (!POOL) {
#pragma unroll
        for (int nt = 0; nt < 4; ++nt) {
            int oc = oc0 + nt * 16 + lm;
            float bs = bias[oc];
#pragma unroll
            for (int mt = 0; mt < MT; ++mt) {
#pragma unroll
                for (int r = 0; r < 4; ++r) {
                    int pos = mt * 16 + lk * 4 + r;
                    int xx = pos & (BX - 1);
                    int yy = wy * WROWS + (pos >> LOG);
                    float v = fmaxf(acc[mt][nt][r] + bs, 0.f);
                    out[((long)(y0 + yy + 1) * (W + 2) + (x0 + xx + 1)) * OC + oc] = (f16)v;
                }
            }
        }
    } else {
        const int Wo = W >> 1;
#pragma unroll
        for (int nt = 0; nt < 4; ++nt) {
            int oc = oc0 + nt * 16 + lm;
            float bs = bias[oc];
#pragma unroll
            for (int mt = 0; mt < 4; ++mt) {
#pragma unroll
                for (int r = 0; r < 4; r += 2) {
                    float v = fmaxf(fmaxf(acc[mt][nt][r], acc[mt][nt][r + 1]),
                                    fmaxf(acc[mt + 4][nt][r], acc[mt + 4][nt][r + 1]));
                    v = fmaxf(v + bs, 0.f);
                    int pos = mt * 16 + lk * 4 + r;
                    int xo = pos >> 1;
                    out[((long)((y0 >> 1) + wy + 1) * (Wo + 2) + ((x0 >> 1) + xo + 1)) * OC + oc] = (f16)v;
                }
            }
        }
    }
}

// ---------------- fused conv1(IC=2)+conv2(64->64)+pool, v3 ----------------
// Light tile (34 KB LDS), NT=2 oc-split (acc=64 VGPR), DEFAULT launch bounds
// (r8's (256,4) clamp spilled acc to scratch: VGPR=64, 1.3 GB/dispatch HBM).
// conv1 im2col gather via u32 channel-pairs (4 dword LDS reads, not 8 f16).
__global__ __launch_bounds__(256) void conv12_k(
    const float* __restrict__ x,   // [8][2][512][512] fp32
    const f16* __restrict__ wt1,   // [64][32], k = 2t+ic, zero-padded
    const float* __restrict__ b1,
    const f16* __restrict__ wt2,   // [9][64][64]
    const float* __restrict__ b2,
    f16* __restrict__ p1, int itemBase, long outStride)
{
    __shared__ f16 ldsx[8 * 68 * 2];     // x tile [r][c][ch]
    __shared__ f16 a1t[6 * 66 * 40];     // conv1 out tile [pix][40] (32 ic + pad)
    const int tid = threadIdx.x;
    const int lane = tid & 63;
    const int wv = tid >> 6;
    const int wy = wv >> 1;
    const int wo = wv & 1;
    const int lm = lane & 15;
    const int lk = lane >> 4;
    const int x0 = blockIdx.x * 64;
    const int y0 = blockIdx.y * 4;
    const float* xb = x + (long)(itemBase + blockIdx.z) * 2 * 512 * 512;
    f16* out = p1 + (long)blockIdx.z * outStride;

    // stage x tile (8 rows x 68 cols x 2 ch), bounds -> 0, cvt f16
    for (int s = tid; s < 8 * 68 * 2; s += 256) {
        int ch = s & 1;
        int v = s >> 1;
        int r = v / 68, c = v - r * 68;
        int gy = y0 + r - 2, gx = x0 + c - 2;
        f16 val = (f16)0.f;
        if ((unsigned)gy < 512u && (unsigned)gx < 512u)
            val = (f16)xb[((long)ch * 512 + gy) * 512 + gx];
        ldsx[s] = val;
    }
    __syncthreads();

    f32x4 acc[8][2];
#pragma unroll
    for (int mt = 0; mt < 8; ++mt)
#pragma unroll
        for (int nt = 0; nt < 2; ++nt)
            acc[mt][nt] = (f32x4){0.f, 0.f, 0.f, 0.f};

    for (int cc = 0; cc < 2; ++cc) {
        if (cc) __syncthreads();   // conv2 chunk-0 reads done before overwrite

        // ---- conv1 -> a1t (ocs cc*32..cc*32+31), 25 tiles strided over 4 waves ----
        {
            float bs0 = b1[cc * 32 + lm];
            float bs1 = b1[cc * 32 + 16 + lm];
            f16x8 bf0 = *(const f16x8*)(wt1 + (cc * 32 + lm) * 32 + lk * 8);
            f16x8 bf1 = *(const f16x8*)(wt1 + (cc * 32 + 16 + lm) * 32 + lk * 8);
            for (int tile = wv; tile < 25; tile += 4) {
                const int pixA = tile * 16 + lm;
                const int pixg = (pixA < 396) ? pixA : 0;
                int rA = (pixg * 993) >> 16;   // /66, valid pix<672
                int cA = pixg - rA * 66;
                union { f16x8 v; unsigned u[4]; } af;
#pragma unroll
                for (int jj = 0; jj < 4; ++jj) {
                    int t = lk * 4 + jj;        // tap; af pair (2jj,2jj+1) = (ch0,ch1)
                    unsigned uv = 0u;
                    if (t < 9) {
                        int dy = (t * 22) >> 6;  // /3 for t<9
                        int dx = t - 3 * dy;
                        uv = *(const unsigned*)&ldsx[((rA + dy) * 68 + (cA + dx)) * 2];
                    }
                    af.u[jj] = uv;
                }
                f32x4 c0 = (f32x4){0.f, 0.f, 0.f, 0.f};
                f32x4 c1 = (f32x4){0.f, 0.f, 0.f, 0.f};
                c0 = mfma16(af.v, bf0, c0);
                c1 = mfma16(af.v, bf1, c1);
#pragma unroll
                for (int rr = 0; rr < 4; ++rr) {
                    int pix = tile * 16 + lk * 4 + rr;
                    if (pix < 396) {
                        int rP = (pix * 993) >> 16;
                        int cP = pix - rP * 66;
                        bool valid = ((unsigned)(y0 + rP - 1) < 512u) &&
                                     ((unsigned)(x0 + cP - 1) < 512u);
                        float v0 = valid ? fmaxf(c0[rr] + bs0, 0.f) : 0.f;
                        float v1 = valid ? fmaxf(c1[rr] + bs1, 0.f) : 0.f;
                        a1t[pix * 40 + lm] = (f16)v0;
                        a1t[pix * 40 + 16 + lm] = (f16)v1;
                    }
                }
            }
        }
        __syncthreads();

        // ---- conv2 chunk cc (t-loop from a1t), MT=8 x NT=2, oc half per wo ----
        const int ic0 = cc * 32;
        for (int t = 0; t < 9; ++t) {
            int dy = t / 3, dx = t - dy * 3;
            const f16* wp = wt2 + ((long)t * 64 + wo * 32) * 64 + ic0 + lk * 8;
            f16x8 bb0 = *(const f16x8*)(wp + (0 * 16 + lm) * 64);
            f16x8 bb1 = *(const f16x8*)(wp + (1 * 16 + lm) * 64);
#pragma unroll
            for (int mt = 0; mt < 8; ++mt) {
                int pos = mt * 16 + lm;
                int xx = pos & 63;
                int yy = wy * 2 + (pos >> 6);
                f16x8 a = *(const f16x8*)&a1t[((yy + dy) * 66 + xx + dx) * 40 + lk * 8];
                acc[mt][0] = mfma16(a, bb0, acc[mt][0]);
                acc[mt][1] = mfma16(a, bb1, acc[mt][1]);
            }
        }
    }

    // pooled epilogue -> p1 [258][258][64]
#pragma unroll
    for (int nt = 0; nt < 2; ++nt) {
        int oc = wo * 32 + nt * 16 + lm;
        float bs = b2[oc];
#pragma unroll
        for (int mt = 0; mt < 4; ++mt) {
#pragma unroll
            for (int r = 0; r < 4; r += 2) {
                float v = fmaxf(fmaxf(acc[mt][nt][r], acc[mt][nt][r + 1]),
                                fmaxf(acc[mt + 4][nt][r], acc[mt + 4][nt][r + 1]));
                v = fmaxf(v + bs, 0.f);
                int pos = mt * 16 + lk * 4 + r;
                int xo = pos >> 1;
                out[((long)((y0 >> 1) + wy + 1) * 258 + ((x0 >> 1) + xo + 1)) * 64 + oc] = (f16)v;
            }
        }
    }
}

// ---------------- fused heads (loc+conf+regr) as one 16-oc MFMA conv ----------------
template<int BX>
__global__ __launch_bounds__(256) void headconv_k(
    const f16* __restrict__ s, long sStride, const f16* __restrict__ wth,
    const float* __restrict__ lb, const float* __restrict__ cb, const float* __restrict__ rb,
    float* __restrict__ loc, float* __restrict__ conf, float* __restrict__ regr,
    int W, int posoff)
{
    constexpr int BY = (BX == 64) ? 1 : 2;
    constexpr int SR = BY + 2, SC = BX + 2;
    constexpr int LOG = (BX == 64) ? 6 : 5;
    __shared__ f16 lds[SR * SC * 40];
    const int tid = threadIdx.x;
    const int lane = tid & 63;
    const int wv = tid >> 6;
    const int lm = lane & 15;
    const int lk = lane >> 4;
    const int y0 = blockIdx.y * BY;
    const int b = blockIdx.z;
    s += (long)b * sStride;

    f32x4 acc = (f32x4){0.f, 0.f, 0.f, 0.f};
    const int Wp = W + 2;
    for (int ic0 = 0; ic0 < 256; ic0 += 32) {
        if (ic0) __syncthreads();
        const f16* ip = s + (long)y0 * Wp * 256 + ic0;
        constexpr int TASKS = SR * SC * 4;
        for (int t = tid; t < TASKS; t += 256) {
            int r = t / (SC * 4);
            int rem = t - r * (SC * 4);
            int xcol = rem >> 2, g = rem & 3;
            f16x8 v = *(const f16x8*)(ip + ((long)r * Wp + xcol) * 256 + g * 8);
            *(f16x8*)&lds[(r * SC + xcol) * 40 + g * 8] = v;
        }
        __syncthreads();
        for (int t = 0; t < 9; ++t) {
            int dy = t / 3, dx = t - dy * 3;
            f16x8 bf = *(const f16x8*)(wth + ((long)t * 16 + lm) * 256 + ic0 + lk * 8);
            int pos = wv * 16 + lm;
            int xx = pos & (BX - 1), yy = pos >> LOG;
            f16x8 a = *(const f16x8*)&lds[((yy + dy) * SC + xx + dx) * 40 + lk * 8];
            acc = mfma16(a, bf, acc);
        }
    }
#pragma unroll
    for (int r = 0; r < 4; ++r) {
        int pos = wv * 16 + lk * 4 + r;
        int xx = pos & (BX - 1), yy = pos >> LOG;
        int P = posoff + (y0 + yy) * W + xx;
        float v = acc[r];
        if (lm < 2)       loc[((long)b * 5120 + P) * 2 + lm]       = v + lb[lm];
        else if (lm < 5)  conf[((long)b * 5120 + P) * 3 + (lm - 2)] = v + cb[lm - 2];
        else if (lm == 5) regr[(long)b * 5120 + P]                  = v + rb[0];
    }
}

// ---------------- small utility kernels ----------------
__global__ __launch_bounds__(256) void cvt_wt_k(const float* __restrict__ w, f16* __restrict__ wt,
                                                int OC, int IC)
{
    int idx = blockIdx.x * 256 + threadIdx.x;
    if (idx >= OC * IC) return;
    int oc = idx / IC, ic = idx - oc * IC;
#pragma unroll
    for (int t = 0; t < 9; ++t)
        wt[((long)t * OC + oc) * IC + ic] = (f16)w[(long)idx * 9 + t];
}

__global__ __launch_bounds__(64) void cvt_wt1_k(const float* __restrict__ w, f16* __restrict__ wt1)
{
    int oc = threadIdx.x;
#pragma unroll
    for (int k = 0; k < 32; ++k) {
        f16 v = (f16)0.f;
        if (k < 18) {
            int t = k >> 1, ic = k & 1;
            v = (f16)w[((long)oc * 2 + ic) * 9 + t];
        }
        wt1[oc * 32 + k] = v;
    }
}

__global__ __launch_bounds__(256) void cvt_wth_k(const float* __restrict__ lw, const float* __restrict__ cw,
                                                 const float* __restrict__ rw, f16* __restrict__ wth)
{
    int idx = blockIdx.x * 256 + threadIdx.x;
    if (idx >= 9 * 16 * 256) return;
    int t = idx / (16 * 256);
    int r = (idx / 256) & 15;
    int ic = idx & 255;
    float v = 0.f;
    if (r < 2)      v = lw[((long)r * 256 + ic) * 9 + t];
    else if (r < 5) v = cw[((long)(r - 2) * 256 + ic) * 9 + t];
    else if (r == 5) v = rw[(long)ic * 9 + t];
    wth[((long)t * 16 + r) * 256 + ic] = (f16)v;
}

__global__ __launch_bounds__(256) void halo_k(f16* __restrict__ buf, int W, int H, int C,
                                              long stride, int items)
{
    int per = (2 * (W + 2) + 2 * H) * C;
    long total = (long)per * items;
    long idx = (long)blockIdx.x * 256 + threadIdx.x;
    if (idx >= total) return;
    int n = idx / per;
    int j = idx - (long)n * per;
    int c = j % C, p = j / C;
    int row, col;
    if (p < W + 2) { row = 0; col = p; }
    else if (p < 2 * (W + 2)) { row = H + 1; col = p - (W + 2); }
    else { int q = p - 2 * (W + 2); row = 1 + (q >> 1); col = (q & 1) ? (W + 1) : 0; }
    buf[(long)n * stride + ((long)row * (W + 2) + col) * C + c] = (f16)0.f;
}

__global__ __launch_bounds__(256) void l2n_k(const f16* __restrict__ in, const float* __restrict__ g,
                                             f16* __restrict__ out, int W, long stride, int total)
{
    int i = blockIdx.x * 256 + threadIdx.x;
    if (i >= total) return;
    int b = i / (W * W);
    int rem = i - b * W * W;
    int y = rem / W, x = rem - y * W;
    long off = (long)b * stride + ((long)(y + 1) * (W + 2) + x + 1) * 256;
    const f16* p = in + off;
    f16* q = out + off;
    float s = 0.f;
    for (int gg = 0; gg < 32; ++gg) {
        f16x8 v = *(const f16x8*)(p + gg * 8);
#pragma unroll
        for (int j = 0; j < 8; ++j) { float f = (float)v[j]; s = fmaf(f, f, s); }
    }
    float inv = 1.f / (sqrtf(s) + 1e-10f);
    for (int gg = 0; gg < 32; ++gg) {
        f16x8 v = *(const f16x8*)(p + gg * 8);
        f16x8 o;
#pragma unroll
        for (int j = 0; j < 8; ++j) o[j] = (f16)(g[gg * 8 + j] * ((float)v[j] * inv));
        *(f16x8*)(q + gg * 8) = o;
    }
}

__global__ __launch_bounds__(256) void mp_k(const f16* __restrict__ in, f16* __restrict__ out)
{
    int idx = blockIdx.x * 256 + threadIdx.x;
    if (idx >= 8 * 32 * 32 * 32) return;
    int gg = idx & 31;
    int xo = (idx >> 5) & 31;
    int yo = (idx >> 10) & 31;
    int b = idx >> 15;
    const f16* p = in + (long)b * 1115136 + ((long)(2 * yo + 1) * 66 + 2 * xo + 1) * 256 + gg * 8;
    f16x8 a0 = *(const f16x8*)p;
    f16x8 a1 = *(const f16x8*)(p + 256);
    f16x8 a2 = *(const f16x8*)(p + 66 * 256);
    f16x8 a3 = *(const f16x8*)(p + 66 * 256 + 256);
    f16x8 o;
#pragma unroll
    for (int j = 0; j < 8; ++j)
        o[j] = (f16)fmaxf(fmaxf((float)a0[j], (float)a1[j]), fmaxf((float)a2[j], (float)a3[j]));
    *(f16x8*)(out + (long)b * 295936 + ((long)(yo + 1) * 34 + xo + 1) * 256 + gg * 8) = o;
}

__global__ __launch_bounds__(256) void priors_k(float* __restrict__ out)
{
    int r = blockIdx.x * 256 + threadIdx.x;
    if (r >= 5120) return;
    float cx, cy;
    if (r < 4096) {
        int i = r >> 6, j = r & 63;
        cx = (j + 0.5f) / 64.0f; cy = (i + 0.5f) / 64.0f;
    } else {
        int rr = r - 4096;
        int i = rr >> 5, j = rr & 31;
        cx = (j + 0.5f) / 32.0f; cy = (i + 0.5f) / 32.0f;
    }
    out[2 * r] = cx;
    out[2 * r + 1] = cy;
}

// ---------------- launch ----------------
extern "C" void kernel_launch(void* const* d_in, const int* in_sizes, int n_in,
                              void* d_out, int out_size, void* d_ws, size_t ws_size,
                              hipStream_t stream)
{
    const float* x  = (const float*)d_in[0];
    const float* w1 = (const float*)d_in[1];  const float* b1 = (const float*)d_in[2];
    const float* w2 = (const float*)d_in[3];  const float* b2 = (const float*)d_in[4];
    const float* w3 = (const float*)d_in[5];  const float* b3 = (const float*)d_in[6];
    const float* w4 = (const float*)d_in[7];  const float* b4 = (const float*)d_in[8];
    const float* w5 = (const float*)d_in[9];  const float* b5 = (const float*)d_in[10];
    const float* w6 = (const float*)d_in[11]; const float* b6 = (const float*)d_in[12];
    const float* w7 = (const float*)d_in[13]; const float* b7 = (const float*)d_in[14];
    const float* w8 = (const float*)d_in[15]; const float* b8 = (const float*)d_in[16];
    const float* g1 = (const float*)d_in[17]; const float* g2 = (const float*)d_in[18];
    const float* lw1 = (const float*)d_in[19]; const float* lb1 = (const float*)d_in[20];
    const float* lw2 = (const float*)d_in[21]; const float* lb2 = (const float*)d_in[22];
    const float* cw1 = (const float*)d_in[23]; const float* cb1 = (const float*)d_in[24];
    const float* cw2 = (const float*)d_in[25]; const float* cb2 = (const float*)d_in[26];
    const float* rw1 = (const float*)d_in[27]; const float* rb1 = (const float*)d_in[28];
    const float* rw2 = (const float*)d_in[29]; const float* rb2 = (const float*)d_in[30];

    f16* wsh = (f16*)d_ws;
    // fixed region (f16 units)
    f16* wt2  = wsh + 0;         // 36864
    f16* wt3  = wsh + 36864;     // 73728
    f16* wt4  = wsh + 110592;    // 147456
    f16* wt5  = wsh + 258048;    // 294912
    f16* wt6  = wsh + 552960;    // 589824
    f16* wt7  = wsh + 1142784;   // 589824
    f16* wt8  = wsh + 1732608;   // 589824
    f16* wt1  = wsh + 2322432;   // 2048
    f16* wth1 = wsh + 2324480;   // 36864
    f16* wth2 = wsh + 2361344;   // 36864
    f16* x6p  = wsh + 2398208;   // 8*66*66*256 = 8921088
    const long PI = 11319296;    // group region base

    // per-item slot: R1 (p1 258x258x64 | p2 130x130x128) + R2 (a3 258x258x128 | a5 130x130x256)
    const long R1S = 4260096;
    const long PS  = 12780288;   // R1S + 8520192
    const long PH2 = 18391040;   // phase-2 footprint (s1..s2)

    int G = 1;
    for (int g = 8; g >= 1; g >>= 1) {
        long ext = (long)g * PS; if (ext < PH2) ext = PH2;
        if (2.0 * (double)(PI + ext) <= (double)ws_size) { G = g; break; }
    }
    const int NGRP = 8 / G;

    f16* p1 = wsh + PI;          // slot stride PS (aliased: p2)
    f16* a3 = wsh + PI + R1S;    // slot stride PS (aliased: a5)
    f16* p2 = p1;
    f16* a5 = a3;
    // phase-2 (after group loop, group region dead)
    f16* s1 = wsh + PI;
    f16* p4 = wsh + PI + 8921088;
    f16* a7 = wsh + PI + 11288576;
    f16* a8 = wsh + PI + 13656064;
    f16* s2 = wsh + PI + 16023552;

    float* loc  = (float*)d_out;
    float* conf = loc + 81920;
    float* regr = loc + 204800;
    float* pri  = loc + 245760;

    // weight conversions
    cvt_wt_k<<<dim3((64 * 64 + 255) / 256), 256, 0, stream>>>(w2, wt2, 64, 64);
    cvt_wt_k<<<dim3((128 * 64 + 255) / 256), 256, 0, stream>>>(w3, wt3, 128, 64);
    cvt_wt_k<<<dim3((128 * 128 + 255) / 256), 256, 0, stream>>>(w4, wt4, 128, 128);
    cvt_wt_k<<<dim3((256 * 128 + 255) / 256), 256, 0, stream>>>(w5, wt5, 256, 128);
    cvt_wt_k<<<dim3((256 * 256 + 255) / 256), 256, 0, stream>>>(w6, wt6, 256, 256);
    cvt_wt_k<<<dim3((256 * 256 + 255) / 256), 256, 0, stream>>>(w7, wt7, 256, 256);
    cvt_wt_k<<<dim3((256 * 256 + 255) / 256), 256, 0, stream>>>(w8, wt8, 256, 256);
    cvt_wt1_k<<<dim3(1), 64, 0, stream>>>(w1, wt1);
    cvt_wth_k<<<dim3(144), 256, 0, stream>>>(lw1, cw1, rw1, wth1);
    cvt_wth_k<<<dim3(144), 256, 0, stream>>>(lw2, cw2, rw2, wth2);

    // conv12..conv6, G items per dispatch; aliased halos re-zeroed in order
    for (int grp = 0; grp < NGRP; ++grp) {
        f16* x6g = x6p + (long)grp * G * 1115136;
        halo_k<<<dim3((G * (2 * 258 + 2 * 256) * 64 + 255) / 256), 256, 0, stream>>>(p1, 256, 256, 64, PS, G);
        halo_k<<<dim3((G * (2 * 258 + 2 * 256) * 128 + 255) / 256), 256, 0, stream>>>(a3, 256, 256, 128, PS, G);
        conv12_k<<<dim3(8, 128, G), 256, 0, stream>>>(x, wt1, b1, wt2, b2, p1, grp * G, PS);
        convmf_k<64, 128, 64, 2, 2, 8, false><<<dim3(4, 64, G), 256, 0, stream>>>(
            p1, wt3, b3, a3, 256, 256, 1, PS, PS);
        halo_k<<<dim3((G * (2 * 130 + 2 * 128) * 128 + 255) / 256), 256, 0, stream>>>(p2, 128, 128, 128, PS, G);
        convmf_k<128, 128, 64, 2, 2, 8, true><<<dim3(4, 64, G), 256, 0, stream>>>(
            a3, wt4, b4, p2, 256, 256, 1, PS, PS);
        halo_k<<<dim3((G * (2 * 130 + 2 * 128) * 256 + 255) / 256), 256, 0, stream>>>(a5, 128, 128, 256, PS, G);
        convmf_k<128, 256, 64, 2, 2, 8, false><<<dim3(2, 32, 2 * G), 256, 0, stream>>>(
            p2, wt5, b5, a5, 128, 128, 2, PS, PS);
        convmf_k<256, 256, 64, 2, 2, 8, true><<<dim3(2, 32, 2 * G), 256, 0, stream>>>(
            a5, wt6, b6, x6g, 128, 128, 2, PS, 1115136);
    }

    // phase-2 halos (group region now dead)
    halo_k<<<dim3((8 * (2 * 66 + 2 * 64) * 256 + 255) / 256), 256, 0, stream>>>(s1, 64, 64, 256, 1115136, 8);
    halo_k<<<dim3((8 * (2 * 34 + 2 * 32) * 256 + 255) / 256), 256, 0, stream>>>(p4, 32, 32, 256, 295936, 8);
    halo_k<<<dim3((8 * (2 * 34 + 2 * 32) * 256 + 255) / 256), 256, 0, stream>>>(a7, 32, 32, 256, 295936, 8);
    halo_k<<<dim3((8 * (2 * 34 + 2 * 32) * 256 + 255) / 256), 256, 0, stream>>>(s2, 32, 32, 256, 295936, 8);

    l2n_k<<<dim3((32768 + 255) / 256), 256, 0, stream>>>(x6p, g1, s1, 64, 1115136, 32768);
    mp_k<<<dim3((262144 + 255) / 256), 256, 0, stream>>>(x6p, p4);
    convmf_k<256, 256, 32, 2, 2, 4, false><<<dim3(1, 8, 16), 256, 0, stream>>>(
        p4, wt7, b7, a7, 32, 32, 2, 295936, 295936);
    convmf_k<256, 256, 32, 2, 2, 4, false><<<dim3(1, 8, 16), 256, 0, stream>>>(
        a7, wt8, b8, a8, 32, 32, 2, 295936, 295936);
    l2n_k<<<dim3((8192 + 255) / 256), 256, 0, stream>>>(a8, g2, s2, 32, 295936, 8192);

    headconv_k<64><<<dim3(1, 64, 8), 256, 0, stream>>>(
        s1, 1115136, wth1, lb1, cb1, rb1, loc, conf, regr, 64, 0);
    headconv_k<32><<<dim3(1, 16, 8), 256, 0, stream>>>(
        s2, 295936, wth2, lb2, cb2, rb2, loc, conf, regr, 32, 4096);
    priors_k<<<dim3(20), 256, 0, stream>>>(pri);

    (void)in_sizes; (void)n_in; (void)out_size; (void)ws_size;
}

// Round 10
// 1177.740 us; speedup vs baseline: 1.8918x; 1.2052x over previous
//
#include <hip/hip_runtime.h>

typedef _Float16 f16;
typedef _Float16 f16x8 __attribute__((ext_vector_type(8)));
typedef float f32x4 __attribute__((ext_vector_type(4)));

__device__ __forceinline__ f32x4 mfma16(f16x8 a, f16x8 b, f32x4 c) {
    return __builtin_amdgcn_mfma_f32_16x16x32_f16(a, b, c, 0, 0, 0);
}

// ---------------- main implicit-GEMM 3x3 conv, f16 MFMA ----------------
// Wave tile: MT m-tiles (MT*16 pos) x NT n-tiles (NT*16 oc). Block: WY x WO waves.
// DEFAULT launch bounds (r8 lesson: a min-waves clamp spills acc to scratch).
template<int IC, int OC, int BX, int WY, int WO, int MT, int NT, bool POOL>
__global__ __launch_bounds__(256) void convmf_k(
    const f16* __restrict__ in, const f16* __restrict__ wt,
    const float* __restrict__ bias, f16* __restrict__ out,
    int H, int W, int ocBlocks, long inStride, long outStride)
{
    constexpr int WROWS = MT * 16 / BX;
    constexpr int BROWS = WROWS * WY;
    constexpr int SR = BROWS + 2;
    constexpr int SC = BX + 2;
    constexpr int LOG = (BX == 64) ? 6 : 5;
    static_assert(!POOL || (BX == 64 && MT == 8), "pool path assumes BX==64, MT==8");
    __shared__ f16 lds[SR * SC * 40];

    const int tid  = threadIdx.x;
    const int lane = tid & 63;
    const int wv   = tid >> 6;
    const int wy   = wv / WO;
    const int wo   = wv % WO;
    const int lm   = lane & 15;
    const int lk   = lane >> 4;
    const int x0   = blockIdx.x * BX;
    const int y0   = blockIdx.y * BROWS;
    const int zb   = blockIdx.z;
    const int n    = zb / ocBlocks;
    const int oc0  = (zb - n * ocBlocks) * (16 * NT * WO) + wo * (16 * NT);
    in  += (long)n * inStride;
    out += (long)n * outStride;

    f32x4 acc[MT][NT];
#pragma unroll
    for (int mt = 0; mt < MT; ++mt)
#pragma unroll
        for (int nt = 0; nt < NT; ++nt)
            acc[mt][nt] = (f32x4){0.f, 0.f, 0.f, 0.f};

    const int Wp = W + 2;
    for (int ic0 = 0; ic0 < IC; ic0 += 32) {
        if (ic0) __syncthreads();
        const f16* ip = in + ((long)y0 * Wp + x0) * IC + ic0;
        constexpr int TASKS = SR * SC * 4;
        for (int s = tid; s < TASKS; s += 256) {
            int r    = s / (SC * 4);
            int rem  = s - r * (SC * 4);
            int xcol = rem >> 2;
            int g    = rem & 3;
            f16x8 v = *(const f16x8*)(ip + ((long)r * Wp + xcol) * IC + g * 8);
            *(f16x8*)&lds[(r * SC + xcol) * 40 + g * 8] = v;
        }
        __syncthreads();

        for (int t = 0; t < 9; ++t) {
            int dy = t / 3, dx = t - dy * 3;
            const f16* wp = wt + ((long)t * OC + oc0) * IC + ic0 + lk * 8;
            f16x8 bfr[NT];
#pragma unroll
            for (int nt = 0; nt < NT; ++nt)
                bfr[nt] = *(const f16x8*)(wp + (nt * 16 + lm) * IC);
#pragma unroll
            for (int mt = 0; mt < MT; ++mt) {
                int pos = mt * 16 + lm;
                int xx = pos & (BX - 1);
                int yy = wy * WROWS + (pos >> LOG);
                f16x8 a = *(const f16x8*)&lds[((yy + dy) * SC + xx + dx) * 40 + lk * 8];
#pragma unroll
                for (int nt = 0; nt < NT; ++nt)
                    acc[mt][nt] = mfma16(a, bfr[nt], acc[mt][nt]);
            }
        }
    }

    if constexpr (!POOL) {
#pragma unroll
        for (int nt = 0; nt < NT; ++nt) {
            int oc = oc0 + nt * 16 + lm;
            float bs = bias[oc];
#pragma unroll
            for (int mt = 0; mt < MT; ++mt) {
#pragma unroll
                for (int r = 0; r < 4; ++r) {
                    int pos = mt * 16 + lk * 4 + r;
                    int xx = pos & (BX - 1);
                    int yy = wy * WROWS + (pos >> LOG);
                    float v = fmaxf(acc[mt][nt][r] + bs, 0.f);
                    out[((long)(y0 + yy + 1) * (W + 2) + (x0 + xx + 1)) * OC + oc] = (f16)v;
                }
            }
        }
    } else {
        const int Wo = W >> 1;
#pragma unroll
        for (int nt = 0; nt < NT; ++nt) {
            int oc = oc0 + nt * 16 + lm;
            float bs = bias[oc];
#pragma unroll
            for (int mt = 0; mt < 4; ++mt) {
#pragma unroll
                for (int r = 0; r < 4; r += 2) {
                    float v = fmaxf(fmaxf(acc[mt][nt][r], acc[mt][nt][r + 1]),
                                    fmaxf(acc[mt + 4][nt][r], acc[mt + 4][nt][r + 1]));
                    v = fmaxf(v + bs, 0.f);
                    int pos = mt * 16 + lk * 4 + r;
                    int xo = pos >> 1;
                    out[((long)((y0 >> 1) + wy + 1) * (Wo + 2) + ((x0 >> 1) + xo + 1)) * OC + oc] = (f16)v;
                }
            }
        }
    }
}

// ---------------- conv1: IC=2, im2col in LDS, K padded to 32 (r5-proven) ----------------
// Reads fp32 x directly (bounds-masked stage, cvt f16); out a1 [514][514][64] per item.
__global__ __launch_bounds__(256) void convmf1_k(
    const float* __restrict__ x, int itemBase,
    const f16* __restrict__ wt1,  // [64][32] f16, k=2t+ic, zero-padded
    const float* __restrict__ bias, f16* __restrict__ out, long outStride)
{
    __shared__ f16 ldsx[10 * 66 * 2];
    __shared__ f16 ldsa[512 * 40];
    const int tid = threadIdx.x;
    const int lane = tid & 63;
    const int wv = tid >> 6;
    const int lm = lane & 15;
    const int lk = lane >> 4;
    const int x0 = blockIdx.x * 64;
    const int y0 = blockIdx.y * 8;
    const float* xb = x + (long)(itemBase + blockIdx.z) * 2 * 512 * 512;
    out += (long)blockIdx.z * outStride;

    for (int s = tid; s < 660; s += 256) {
        int r = s / 66, xc = s - r * 66;
        int gy = y0 + r - 1, gx = x0 + xc - 1;
        f16 v0 = (f16)0.f, v1 = (f16)0.f;
        if ((unsigned)gy < 512u && (unsigned)gx < 512u) {
            v0 = (f16)xb[(long)gy * 512 + gx];
            v1 = (f16)xb[262144 + (long)gy * 512 + gx];
        }
        ldsx[(r * 66 + xc) * 2]     = v0;
        ldsx[(r * 66 + xc) * 2 + 1] = v1;
    }
    __syncthreads();
    for (int s = tid; s < 2048; s += 256) {
        int pos = s >> 2, g = s & 3;
        int row = pos >> 6, col = pos & 63;
        f16x8 v;
#pragma unroll
        for (int j = 0; j < 8; ++j) {
            int k = g * 8 + j;
            f16 val = (f16)0.f;
            if (k < 18) {
                int t = k >> 1, ic = k & 1;
                int dy = t / 3, dx = t - dy * 3;
                val = ldsx[((row + dy) * 66 + col + dx) * 2 + ic];
            }
            v[j] = val;
        }
        *(f16x8*)&ldsa[pos * 40 + g * 8] = v;
    }
    __syncthreads();

    f32x4 acc[8][4];
#pragma unroll
    for (int mt = 0; mt < 8; ++mt)
#pragma unroll
        for (int nt = 0; nt < 4; ++nt)
            acc[mt][nt] = (f32x4){0.f, 0.f, 0.f, 0.f};

    f16x8 b0 = *(const f16x8*)(wt1 + (0 * 16 + lm) * 32 + lk * 8);
    f16x8 b1 = *(const f16x8*)(wt1 + (1 * 16 + lm) * 32 + lk * 8);
    f16x8 b2 = *(const f16x8*)(wt1 + (2 * 16 + lm) * 32 + lk * 8);
    f16x8 b3 = *(const f16x8*)(wt1 + (3 * 16 + lm) * 32 + lk * 8);
#pragma unroll
    for (int mt = 0; mt < 8; ++mt) {
        int pos = wv * 128 + mt * 16 + lm;
        f16x8 a = *(const f16x8*)&ldsa[pos * 40 + lk * 8];
        acc[mt][0] = mfma16(a, b0, acc[mt][0]);
        acc[mt][1] = mfma16(a, b1, acc[mt][1]);
        acc[mt][2] = mfma16(a, b2, acc[mt][2]);
        acc[mt][3] = mfma16(a, b3, acc[mt][3]);
    }
#pragma unroll
    for (int nt = 0; nt < 4; ++nt) {
        int oc = nt * 16 + lm;
        float bs = bias[oc];
#pragma unroll
        for (int mt = 0; mt < 8; ++mt) {
#pragma unroll
            for (int r = 0; r < 4; ++r) {
                int pos = wv * 128 + mt * 16 + lk * 4 + r;
                int xx = pos & 63, yy = pos >> 6;
                float v = fmaxf(acc[mt][nt][r] + bs, 0.f);
                out[((long)(y0 + yy + 1) * 514 + (x0 + xx + 1)) * 64 + oc] = (f16)v;
            }
        }
    }
}

// ---------------- fused heads (loc+conf+regr) as one 16-oc MFMA conv ----------------
template<int BX>
__global__ __launch_bounds__(256) void headconv_k(
    const f16* __restrict__ s, long sStride, const f16* __restrict__ wth,
    const float* __restrict__ lb, const float* __restrict__ cb, const float* __restrict__ rb,
    float* __restrict__ loc, float* __restrict__ conf, float* __restrict__ regr,
    int W, int posoff)
{
    constexpr int BY = (BX == 64) ? 1 : 2;
    constexpr int SR = BY + 2, SC = BX + 2;
    constexpr int LOG = (BX == 64) ? 6 : 5;
    __shared__ f16 lds[SR * SC * 40];
    const int tid = threadIdx.x;
    const int lane = tid & 63;
    const int wv = tid >> 6;
    const int lm = lane & 15;
    const int lk = lane >> 4;
    const int y0 = blockIdx.y * BY;
    const int b = blockIdx.z;
    s += (long)b * sStride;

    f32x4 acc = (f32x4){0.f, 0.f, 0.f, 0.f};
    const int Wp = W + 2;
    for (int ic0 = 0; ic0 < 256; ic0 += 32) {
        if (ic0) __syncthreads();
        const f16* ip = s + (long)y0 * Wp * 256 + ic0;
        constexpr int TASKS = SR * SC * 4;
        for (int t = tid; t < TASKS; t += 256) {
            int r = t / (SC * 4);
            int rem = t - r * (SC * 4);
            int xcol = rem >> 2, g = rem & 3;
            f16x8 v = *(const f16x8*)(ip + ((long)r * Wp + xcol) * 256 + g * 8);
            *(f16x8*)&lds[(r * SC + xcol) * 40 + g * 8] = v;
        }
        __syncthreads();
        for (int t = 0; t < 9; ++t) {
            int dy = t / 3, dx = t - dy * 3;
            f16x8 bf = *(const f16x8*)(wth + ((long)t * 16 + lm) * 256 + ic0 + lk * 8);
            int pos = wv * 16 + lm;
            int xx = pos & (BX - 1), yy = pos >> LOG;
            f16x8 a = *(const f16x8*)&lds[((yy + dy) * SC + xx + dx) * 40 + lk * 8];
            acc = mfma16(a, bf, acc);
        }
    }
#pragma unroll
    for (int r = 0; r < 4; ++r) {
        int pos = wv * 16 + lk * 4 + r;
        int xx = pos & (BX - 1), yy = pos >> LOG;
        int P = posoff + (y0 + yy) * W + xx;
        float v = acc[r];
        if (lm < 2)       loc[((long)b * 5120 + P) * 2 + lm]       = v + lb[lm];
        else if (lm < 5)  conf[((long)b * 5120 + P) * 3 + (lm - 2)] = v + cb[lm - 2];
        else if (lm == 5) regr[(long)b * 5120 + P]                  = v + rb[0];
    }
}

// ---------------- small utility kernels ----------------
__global__ __launch_bounds__(256) void cvt_wt_k(const float* __restrict__ w, f16* __restrict__ wt,
                                                int OC, int IC)
{
    int idx = blockIdx.x * 256 + threadIdx.x;
    if (idx >= OC * IC) return;
    int oc = idx / IC, ic = idx - oc * IC;
#pragma unroll
    for (int t = 0; t < 9; ++t)
        wt[((long)t * OC + oc) * IC + ic] = (f16)w[(long)idx * 9 + t];
}

__global__ __launch_bounds__(64) void cvt_wt1_k(const float* __restrict__ w, f16* __restrict__ wt1)
{
    int oc = threadIdx.x;
#pragma unroll
    for (int k = 0; k < 32; ++k) {
        f16 v = (f16)0.f;
        if (k < 18) {
            int t = k >> 1, ic = k & 1;
            v = (f16)w[((long)oc * 2 + ic) * 9 + t];
        }
        wt1[oc * 32 + k] = v;
    }
}

__global__ __launch_bounds__(256) void cvt_wth_k(const float* __restrict__ lw, const float* __restrict__ cw,
                                                 const float* __restrict__ rw, f16* __restrict__ wth)
{
    int idx = blockIdx.x * 256 + threadIdx.x;
    if (idx >= 9 * 16 * 256) return;
    int t = idx / (16 * 256);
    int r = (idx / 256) & 15;
    int ic = idx & 255;
    float v = 0.f;
    if (r < 2)      v = lw[((long)r * 256 + ic) * 9 + t];
    else if (r < 5) v = cw[((long)(r - 2) * 256 + ic) * 9 + t];
    else if (r == 5) v = rw[(long)ic * 9 + t];
    wth[((long)t * 16 + r) * 256 + ic] = (f16)v;
}

__global__ __launch_bounds__(256) void halo_k(f16* __restrict__ buf, int W, int H, int C,
                                              long stride, int items)
{
    int per = (2 * (W + 2) + 2 * H) * C;
    long total = (long)per * items;
    long idx = (long)blockIdx.x * 256 + threadIdx.x;
    if (idx >= total) return;
    int n = idx / per;
    int j = idx - (long)n * per;
    int c = j % C, p = j / C;
    int row, col;
    if (p < W + 2) { row = 0; col = p; }
    else if (p < 2 * (W + 2)) { row = H + 1; col = p - (W + 2); }
    else { int q = p - 2 * (W + 2); row = 1 + (q >> 1); col = (q & 1) ? (W + 1) : 0; }
    buf[(long)n * stride + ((long)row * (W + 2) + col) * C + c] = (f16)0.f;
}

__global__ __launch_bounds__(256) void l2n_k(const f16* __restrict__ in, const float* __restrict__ g,
                                             f16* __restrict__ out, int W, long stride, int total)
{
    int i = blockIdx.x * 256 + threadIdx.x;
    if (i >= total) return;
    int b = i / (W * W);
    int rem = i - b * W * W;
    int y = rem / W, x = rem - y * W;
    long off = (long)b * stride + ((long)(y + 1) * (W + 2) + x + 1) * 256;
    const f16* p = in + off;
    f16* q = out + off;
    float s = 0.f;
    for (int gg = 0; gg < 32; ++gg) {
        f16x8 v = *(const f16x8*)(p + gg * 8);
#pragma unroll
        for (int j = 0; j < 8; ++j) { float f = (float)v[j]; s = fmaf(f, f, s); }
    }
    float inv = 1.f / (sqrtf(s) + 1e-10f);
    for (int gg = 0; gg < 32; ++gg) {
        f16x8 v = *(const f16x8*)(p + gg * 8);
        f16x8 o;
#pragma unroll
        for (int j = 0; j < 8; ++j) o[j] = (f16)(g[gg * 8 + j] * ((float)v[j] * inv));
        *(f16x8*)(q + gg * 8) = o;
    }
}

__global__ __launch_bounds__(256) void mp_k(const f16* __restrict__ in, f16* __restrict__ out)
{
    int idx = blockIdx.x * 256 + threadIdx.x;
    if (idx >= 8 * 32 * 32 * 32) return;
    int gg = idx & 31;
    int xo = (idx >> 5) & 31;
    int yo = (idx >> 10) & 31;
    int b = idx >> 15;
    const f16* p = in + (long)b * 1115136 + ((long)(2 * yo + 1) * 66 + 2 * xo + 1) * 256 + gg * 8;
    f16x8 a0 = *(const f16x8*)p;
    f16x8 a1 = *(const f16x8*)(p + 256);
    f16x8 a2 = *(const f16x8*)(p + 66 * 256);
    f16x8 a3 = *(const f16x8*)(p + 66 * 256 + 256);
    f16x8 o;
#pragma unroll
    for (int j = 0; j < 8; ++j)
        o[j] = (f16)fmaxf(fmaxf((float)a0[j], (float)a1[j]), fmaxf((float)a2[j], (float)a3[j]));
    *(f16x8*)(out + (long)b * 295936 + ((long)(yo + 1) * 34 + xo + 1) * 256 + gg * 8) = o;
}

__global__ __launch_bounds__(256) void priors_k(float* __restrict__ out)
{
    int r = blockIdx.x * 256 + threadIdx.x;
    if (r >= 5120) return;
    float cx, cy;
    if (r < 4096) {
        int i = r >> 6, j = r & 63;
        cx = (j + 0.5f) / 64.0f; cy = (i + 0.5f) / 64.0f;
    } else {
        int rr = r - 4096;
        int i = rr >> 5, j = rr & 31;
        cx = (j + 0.5f) / 32.0f; cy = (i + 0.5f) / 32.0f;
    }
    out[2 * r] = cx;
    out[2 * r + 1] = cy;
}

// ---------------- launch ----------------
extern "C" void kernel_launch(void* const* d_in, const int* in_sizes, int n_in,
                              void* d_out, int out_size, void* d_ws, size_t ws_size,
                              hipStream_t stream)
{
    const float* x  = (const float*)d_in[0];
    const float* w1 = (const float*)d_in[1];  const float* b1 = (const float*)d_in[2];
    const float* w2 = (const float*)d_in[3];  const float* b2 = (const float*)d_in[4];
    const float* w3 = (const float*)d_in[5];  const float* b3 = (const float*)d_in[6];
    const float* w4 = (const float*)d_in[7];  const float* b4 = (const float*)d_in[8];
    const float* w5 = (const float*)d_in[9];  const float* b5 = (const float*)d_in[10];
    const float* w6 = (const float*)d_in[11]; const float* b6 = (const float*)d_in[12];
    const float* w7 = (const float*)d_in[13]; const float* b7 = (const float*)d_in[14];
    const float* w8 = (const float*)d_in[15]; const float* b8 = (const float*)d_in[16];
    const float* g1 = (const float*)d_in[17]; const float* g2 = (const float*)d_in[18];
    const float* lw1 = (const float*)d_in[19]; const float* lb1 = (const float*)d_in[20];
    const float* lw2 = (const float*)d_in[21]; const float* lb2 = (const float*)d_in[22];
    const float* cw1 = (const float*)d_in[23]; const float* cb1 = (const float*)d_in[24];
    const float* cw2 = (const float*)d_in[25]; const float* cb2 = (const float*)d_in[26];
    const float* rw1 = (const float*)d_in[27]; const float* rb1 = (const float*)d_in[28];
    const float* rw2 = (const float*)d_in[29]; const float* rb2 = (const float*)d_in[30];

    f16* wsh = (f16*)d_ws;
    // fixed region (f16 units)
    f16* wt2  = wsh + 0;         // 36864
    f16* wt3  = wsh + 36864;     // 73728
    f16* wt4  = wsh + 110592;    // 147456
    f16* wt5  = wsh + 258048;    // 294912
    f16* wt6  = wsh + 552960;    // 589824
    f16* wt7  = wsh + 1142784;   // 589824
    f16* wt8  = wsh + 1732608;   // 589824
    f16* wt1  = wsh + 2322432;   // 2048
    f16* wth1 = wsh + 2324480;   // 36864
    f16* wth2 = wsh + 2361344;   // 36864
    f16* x6p  = wsh + 2398208;   // 8*66*66*256 = 8921088
    const long PI = 11319296;    // group region base

    // per-item strides (f16 units); slot = a1 region (G*A1S) + p1 region (G*P1S)
    const long A1S = 16908544;   // 514*514*64
    const long P1S = 4260096;    // 258*258*64
    const long A3S = 8520192;    // 258*258*128 (aliases a1 region)
    const long P2S = 2163200;    // 130*130*128 (aliases p1 region)
    const long A5S = 4326400;    // 130*130*256 (aliases a1 region)
    const long PH2 = 18391040;   // phase-2 footprint (s1..s2)

    int G = 1;
    for (int g = 8; g >= 1; g >>= 1) {
        long ext = (long)g * (A1S + P1S); if (ext < PH2) ext = PH2;
        if (2.0 * (double)(PI + ext) <= (double)ws_size) { G = g; break; }
    }
    const int NGRP = 8 / G;

    f16* a1 = wsh + PI;                    // G x A1S (aliased: a3 G x A3S, a5 G x A5S)
    f16* p1 = wsh + PI + (long)G * A1S;    // G x P1S (aliased: p2 G x P2S)
    f16* a3 = a1;
    f16* p2 = p1;
    f16* a5 = a1;
    // phase-2 (after group loop, group region dead)
    f16* s1 = wsh + PI;
    f16* p4 = wsh + PI + 8921088;
    f16* a7 = wsh + PI + 11288576;
    f16* a8 = wsh + PI + 13656064;
    f16* s2 = wsh + PI + 16023552;

    float* loc  = (float*)d_out;
    float* conf = loc + 81920;
    float* regr = loc + 204800;
    float* pri  = loc + 245760;

    // weight conversions
    cvt_wt_k<<<dim3((64 * 64 + 255) / 256), 256, 0, stream>>>(w2, wt2, 64, 64);
    cvt_wt_k<<<dim3((128 * 64 + 255) / 256), 256, 0, stream>>>(w3, wt3, 128, 64);
    cvt_wt_k<<<dim3((128 * 128 + 255) / 256), 256, 0, stream>>>(w4, wt4, 128, 128);
    cvt_wt_k<<<dim3((256 * 128 + 255) / 256), 256, 0, stream>>>(w5, wt5, 256, 128);
    cvt_wt_k<<<dim3((256 * 256 + 255) / 256), 256, 0, stream>>>(w6, wt6, 256, 256);
    cvt_wt_k<<<dim3((256 * 256 + 255) / 256), 256, 0, stream>>>(w7, wt7, 256, 256);
    cvt_wt_k<<<dim3((256 * 256 + 255) / 256), 256, 0, stream>>>(w8, wt8, 256, 256);
    cvt_wt1_k<<<dim3(1), 64, 0, stream>>>(w1, wt1);
    cvt_wth_k<<<dim3(144), 256, 0, stream>>>(lw1, cw1, rw1, wth1);
    cvt_wth_k<<<dim3(144), 256, 0, stream>>>(lw2, cw2, rw2, wth2);

    // conv1..conv6, G items per dispatch; aliased halos re-zeroed in r5-proven order
    for (int grp = 0; grp < NGRP; ++grp) {
        f16* x6g = x6p + (long)grp * G * 1115136;
        halo_k<<<dim3((G * (2 * 514 + 2 * 512) * 64 + 255) / 256), 256, 0, stream>>>(a1, 512, 512, 64, A1S, G);
        halo_k<<<dim3((G * (2 * 258 + 2 * 256) * 64 + 255) / 256), 256, 0, stream>>>(p1, 256, 256, 64, P1S, G);
        convmf1_k<<<dim3(8, 64, G), 256, 0, stream>>>(x, grp * G, wt1, b1, a1, A1S);
        convmf_k<64, 64, 64, 2, 2, 8, 2, true><<<dim3(8, 128, G), 256, 0, stream>>>(
            a1, wt2, b2, p1, 512, 512, 1, A1S, P1S);
        halo_k<<<dim3((G * (2 * 258 + 2 * 256) * 128 + 255) / 256), 256, 0, stream>>>(a3, 256, 256, 128, A3S, G);
        convmf_k<64, 128, 64, 2, 2, 8, 2, false><<<dim3(4, 64, 2 * G), 256, 0, stream>>>(
            p1, wt3, b3, a3, 256, 256, 2, P1S, A3S);
        halo_k<<<dim3((G * (2 * 130 + 2 * 128) * 128 + 255) / 256), 256, 0, stream>>>(p2, 128, 128, 128, P2S, G);
        convmf_k<128, 128, 64, 2, 2, 8, 2, true><<<dim3(4, 64, 2 * G), 256, 0, stream>>>(
            a3, wt4, b4, p2, 256, 256, 2, A3S, P2S);
        halo_k<<<dim3((G * (2 * 130 + 2 * 128) * 256 + 255) / 256), 256, 0, stream>>>(a5, 128, 128, 256, A5S, G);
        convmf_k<128, 256, 64, 2, 2, 8, 2, false><<<dim3(2, 32, 4 * G), 256, 0, stream>>>(
            p2, wt5, b5, a5, 128, 128, 4, P2S, A5S);
        convmf_k<256, 256, 64, 2, 2, 8, 2, true><<<dim3(2, 32, 4 * G), 256, 0, stream>>>(
            a5, wt6, b6, x6g, 128, 128, 4, A5S, 1115136);
    }

    // phase-2 halos (group region now dead)
    halo_k<<<dim3((8 * (2 * 66 + 2 * 64) * 256 + 255) / 256), 256, 0, stream>>>(s1, 64, 64, 256, 1115136, 8);
    halo_k<<<dim3((8 * (2 * 34 + 2 * 32) * 256 + 255) / 256), 256, 0, stream>>>(p4, 32, 32, 256, 295936, 8);
    halo_k<<<dim3((8 * (2 * 34 + 2 * 32) * 256 + 255) / 256), 256, 0, stream>>>(a7, 32, 32, 256, 295936, 8);
    halo_k<<<dim3((8 * (2 * 34 + 2 * 32) * 256 + 255) / 256), 256, 0, stream>>>(s2, 32, 32, 256, 295936, 8);

    l2n_k<<<dim3((32768 + 255) / 256), 256, 0, stream>>>(x6p, g1, s1, 64, 1115136, 32768);
    mp_k<<<dim3((262144 + 255) / 256), 256, 0, stream>>>(x6p, p4);
    convmf_k<256, 256, 32, 2, 2, 4, 4, false><<<dim3(1, 8, 16), 256, 0, stream>>>(
        p4, wt7, b7, a7, 32, 32, 2, 295936, 295936);
    convmf_k<256, 256, 32, 2, 2, 4, 4, false><<<dim3(1, 8, 16), 256, 0, stream>>>(
        a7, wt8, b8, a8, 32, 32, 2, 295936, 295936);
    l2n_k<<<dim3((8192 + 255) / 256), 256, 0, stream>>>(a8, g2, s2, 32, 295936, 8192);

    headconv_k<64><<<dim3(1, 64, 8), 256, 0, stream>>>(
        s1, 1115136, wth1, lb1, cb1, rb1, loc, conf, regr, 64, 0);
    headconv_k<32><<<dim3(1, 16, 8), 256, 0, stream>>>(
        s2, 295936, wth2, lb2, cb2, rb2, loc, conf, regr, 32, 4096);
    priors_k<<<dim3(20), 256, 0, stream>>>(pri);

    (void)in_sizes; (void)n_in; (void)out_size; (void)ws_size;
}